// Round 10
// baseline (679.731 us; speedup 1.0000x reference)
//
#include <hip/hip_runtime.h>
#include <hip/hip_cooperative_groups.h>

namespace cg = cooperative_groups;

#define N_NODES 100000
#define N_EDGES 3200000
#define NF 256
#define HID 64
#define BSHIFT 7
#define NBUCK 782                       // ceil(100000 / 128)
#define NP1 512                         // phase-1 partition blocks
#define CHUNKE (N_EDGES / NP1)          // 6250 exactly (even)
#define MAXB 5120                       // p2ab LDS sort capacity per bucket
#define NQ 25000                        // src-partition width (h tile = 3.2 MB < 4 MB L2)
#define NBB 391                         // coop blocks (2 buckets = 256 dsts each)

typedef short short8 __attribute__((ext_vector_type(8)));
typedef float f32x4 __attribute__((ext_vector_type(4)));

__device__ __forceinline__ unsigned short f2bf(float v) {
    unsigned int u = __float_as_uint(v);
    u += 0x7FFFu + ((u >> 16) & 1u);
    return (unsigned short)(u >> 16);
}
__device__ __forceinline__ float bfl(unsigned int p) { return __uint_as_float((p & 0xFFFFu) << 16); }
__device__ __forceinline__ float bfh(unsigned int p) { return __uint_as_float(p & 0xFFFF0000u); }

// ---------- 1a: per-block LDS histogram + folded one-time W1 swizzle ----------
__launch_bounds__(256)
__global__ void p1count(const int* __restrict__ ei, unsigned int* __restrict__ blkhist,
                        const float* __restrict__ W, unsigned short* __restrict__ wsw) {
    __shared__ unsigned int hist[NBUCK];
    if (blockIdx.x < 64) {
        int idx = blockIdx.x * 256 + threadIdx.x;
        int j = idx & 7;
        int lane = (idx >> 3) & 63;
        int ntile = (idx >> 9) & 3;
        int kiter = idx >> 11;
        int k = kiter * 32 + (lane >> 4) * 8 + j;
        int n = ntile * 16 + (lane & 15);
        wsw[idx] = f2bf(W[k * HID + n]);
    }
    for (int i = threadIdx.x; i < NBUCK; i += 256) hist[i] = 0;
    __syncthreads();
    int lo = blockIdx.x * CHUNKE;
    int hi = lo + CHUNKE;
    for (int e = lo + 2 * threadIdx.x; e < hi; e += 512) {
        int2 d2 = *(const int2*)&ei[N_EDGES + e];
        atomicAdd(&hist[((unsigned)d2.x) >> BSHIFT], 1u);
        atomicAdd(&hist[((unsigned)d2.y) >> BSHIFT], 1u);
    }
    __syncthreads();
    unsigned int* row = blkhist + (size_t)blockIdx.x * NBUCK;
    for (int i = threadIdx.x; i < NBUCK; i += 256) row[i] = hist[i];
}

// ---------- 1b: column reduce -> bucket_total[bucket] ----------
__launch_bounds__(256)
__global__ void bktA(const unsigned int* __restrict__ blkhist, unsigned int* __restrict__ total) {
    __shared__ unsigned int sh[256];
    int i = blockIdx.x;              // bucket
    int t = threadIdx.x;
    unsigned s = 0;
    for (int b = t; b < NP1; b += 256) s += blkhist[(size_t)b * NBUCK + i];
    sh[t] = s;
    __syncthreads();
    for (int off = 128; off > 0; off >>= 1) {
        if (t < off) sh[t] += sh[t + off];
        __syncthreads();
    }
    if (t == 0) total[i] = sh[0];
}

// ---------- 1cd merged: base_i reduction + per-bucket scan across blocks ----------
__launch_bounds__(256)
__global__ void bktC(const unsigned int* __restrict__ blkhist, const unsigned int* __restrict__ total,
                     unsigned int* __restrict__ blkbase, unsigned int* __restrict__ base) {
    __shared__ unsigned int sh[256];
    int i = blockIdx.x;              // bucket
    int t = threadIdx.x;

    unsigned bs = 0;
    for (int j = t; j < i; j += 256) bs += total[j];
    sh[t] = bs;
    __syncthreads();
    for (int off = 128; off > 0; off >>= 1) {
        if (t < off) sh[t] += sh[t + off];
        __syncthreads();
    }
    unsigned base_i = sh[0];
    __syncthreads();
    if (t == 0) {
        base[i] = base_i;
        if (i == 0) base[NBUCK] = N_EDGES;
    }

    unsigned c[2];
    unsigned s = 0;
#pragma unroll
    for (int j = 0; j < 2; ++j) {
        c[j] = blkhist[(size_t)(2 * t + j) * NBUCK + i];
        s += c[j];
    }
    sh[t] = s;
    __syncthreads();
    for (int off = 1; off < 256; off <<= 1) {
        unsigned a = (t >= off) ? sh[t - off] : 0;
        __syncthreads();
        sh[t] += a;
        __syncthreads();
    }
    unsigned run = base_i + sh[t] - s;
    unsigned int* orow = blkbase + (size_t)i * NP1 + 2 * t;
    orow[0] = run; run += c[0];
    orow[1] = run;
}

// ---------- 1e: staged scatter — LDS counting sort, then coalesced run write-out ----------
__launch_bounds__(256)
__global__ void p1scatter(const int* __restrict__ ei, const float* __restrict__ ew,
                          const unsigned int* __restrict__ blkhist,
                          const unsigned int* __restrict__ blkbase, int2* __restrict__ pbuf) {
    __shared__ int2 sorted[CHUNKE];           // 50000 B
    __shared__ unsigned int loff[NBUCK + 2];
    __shared__ unsigned int cur[NBUCK];
    __shared__ unsigned int sh[256];

    int t = threadIdx.x;
    int b = blockIdx.x;

    unsigned u[4];
    unsigned s = 0;
#pragma unroll
    for (int j = 0; j < 4; ++j) {
        int idx = 4 * t + j;
        u[j] = (idx < NBUCK) ? blkhist[(size_t)b * NBUCK + idx] : 0u;
        s += u[j];
    }
    sh[t] = s;
    __syncthreads();
    for (int off = 1; off < 256; off <<= 1) {
        unsigned a = (t >= off) ? sh[t - off] : 0;
        __syncthreads();
        sh[t] += a;
        __syncthreads();
    }
    unsigned run = sh[t] - s;
#pragma unroll
    for (int j = 0; j < 4; ++j) {
        int idx = 4 * t + j;
        if (idx <= NBUCK) loff[idx] = run;
        run += u[j];
        if (idx < NBUCK) cur[idx] = 0;
    }
    __syncthreads();

    int lo = b * CHUNKE;
    int hi = lo + CHUNKE;
    for (int e = lo + 2 * t; e < hi; e += 512) {
        int2 s2 = *(const int2*)&ei[e];
        int2 d2 = *(const int2*)&ei[N_EDGES + e];
        float2 w2 = *(const float2*)&ew[e];
        unsigned k0 = ((unsigned)d2.x) >> BSHIFT;
        unsigned r0 = atomicAdd(&cur[k0], 1u);
        sorted[loff[k0] + r0] = make_int2(s2.x | (int)(((unsigned)d2.x & 127u) << 17), __float_as_int(w2.x));
        unsigned k1 = ((unsigned)d2.y) >> BSHIFT;
        unsigned r1 = atomicAdd(&cur[k1], 1u);
        sorted[loff[k1] + r1] = make_int2(s2.y | (int)(((unsigned)d2.y & 127u) << 17), __float_as_int(w2.y));
    }
    __syncthreads();

    int lane = t & 63;
    int wave = t >> 6;
    int q = lane >> 3;
    int r8 = lane & 7;
    for (int k0 = wave * 8; k0 < NBUCK; k0 += 32) {
        int k = k0 + q;
        if (k < NBUCK) {
            unsigned off = loff[k];
            int n = (int)(loff[k + 1] - off);
            unsigned gb = blkbase[(size_t)k * NP1 + b];
            for (int i = r8; i < n; i += 8)
                pbuf[gb + i] = sorted[off + i];
        }
    }
}

// ---------- phase 2: 512-bin (dst_low7, src/25000) sort + deg/dinv + rp4 CSR ----------
// ebuf stores (src, raw ew); runs ordered by (dl, srcp) within each bucket.
__launch_bounds__(256)
__global__ void p2ab(const int2* __restrict__ pbuf, const unsigned int* __restrict__ base,
                     float* __restrict__ dinv, int* __restrict__ rp4, int2* __restrict__ ebuf) {
    __shared__ int lcnt[512];
    __shared__ float ldeg[128];
    __shared__ int sc[256];
    __shared__ int loff[512];
    __shared__ unsigned int lcur[512];
    __shared__ int2 sorted[MAXB];    // 40 KB  (total LDS ~47.5 KB)

    int t = threadIdx.x;
    int bkt = blockIdx.x;
    unsigned b0 = base[bkt], bh = base[bkt + 1];
    int nb = (int)(bh - b0);
    int d0 = bkt << BSHIFT;
    int nd = N_NODES - d0; if (nd > 128) nd = 128;

    lcnt[t] = 0; lcnt[t + 256] = 0;
    lcur[t] = 0; lcur[t + 256] = 0;
    if (t < 128) ldeg[t] = 0.f;
    __syncthreads();

    // pass 1: per-key counts + weighted degree per dl
    for (int i = t; i < nb; i += 256) {
        int2 e = pbuf[b0 + i];
        int dl = (e.x >> 17) & 127;
        unsigned src = (unsigned)(e.x & 0x1FFFF);
        int key = (dl << 2) | (int)(src / (unsigned)NQ);
        atomicAdd(&lcnt[key], 1);
        atomicAdd(&ldeg[dl], __int_as_float(e.y));
    }
    __syncthreads();

    // exclusive scan over 512 keys (2 per thread)
    int c0 = lcnt[2 * t], c1 = lcnt[2 * t + 1];
    int s = c0 + c1;
    sc[t] = s;
    __syncthreads();
    for (int off = 1; off < 256; off <<= 1) {
        int a = (t >= off) ? sc[t - off] : 0;
        __syncthreads();
        sc[t] += a;
        __syncthreads();
    }
    int excl = sc[t] - s;
    loff[2 * t] = excl;
    loff[2 * t + 1] = excl + c0;
    __syncthreads();

    // rp4 write (coalesced): flat[4*d0 + key] = b0 + loff[key]
    if ((t >> 2) < nd) rp4[4 * d0 + t] = (int)(b0 + (unsigned)loff[t]);
    {
        int k2 = t + 256;
        if ((k2 >> 2) < nd) rp4[4 * d0 + k2] = (int)(b0 + (unsigned)loff[k2]);
    }
    if (t < 128 && t < nd) dinv[d0 + t] = rsqrtf(ldeg[t] + 1.0f);
    if (bkt == NBUCK - 1 && t == 0) rp4[4 * N_NODES] = N_EDGES;
    __syncthreads();

    if (nb <= MAXB) {
        for (int i = t; i < nb; i += 256) {
            int2 e = pbuf[b0 + i];
            int sidx = e.x & 0x1FFFF;
            int dl = (e.x >> 17) & 127;
            int key = (dl << 2) | (int)((unsigned)sidx / (unsigned)NQ);
            unsigned r = atomicAdd(&lcur[key], 1u);
            sorted[loff[key] + (int)r] = make_int2(sidx, e.y);
        }
        __syncthreads();
        for (int i = t; i < nb; i += 256) ebuf[b0 + i] = sorted[i];
    } else {
        for (int i = t; i < nb; i += 256) {
            int2 e = pbuf[b0 + i];
            int sidx = e.x & 0x1FFFF;
            int dl = (e.x >> 17) & 127;
            int key = (dl << 2) | (int)((unsigned)sidx / (unsigned)NQ);
            unsigned r = atomicAdd(&lcur[key], 1u);
            ebuf[b0 + loff[key] + r] = make_int2(sidx, e.y);
        }
    }
}

// ---------- h' = dinv[row] * (x @ W1) via MFMA ----------
__launch_bounds__(256)
__global__ void gemm1_mfma(const float* __restrict__ x, const unsigned short* __restrict__ wsw,
                           const float* __restrict__ dinv, unsigned short* __restrict__ h) {
    int t = threadIdx.x;
    int lane = t & 63;
    int wave = t >> 6;
    int m = lane & 15;
    int quad = lane >> 4;
    int rowbase = blockIdx.x * 64 + wave * 16;

    int row = rowbase + m;
    if (row >= N_NODES) row = N_NODES - 1;

    const short8* wv = (const short8*)wsw;

    f32x4 acc[4] = {{0.f,0.f,0.f,0.f},{0.f,0.f,0.f,0.f},{0.f,0.f,0.f,0.f},{0.f,0.f,0.f,0.f}};

    const float* xrow = x + (size_t)row * NF;
#pragma unroll
    for (int kiter = 0; kiter < 8; ++kiter) {
        int k0 = kiter * 32 + quad * 8;
        float4 xa = *(const float4*)&xrow[k0];
        float4 xb = *(const float4*)&xrow[k0 + 4];
        short8 a;
        a[0] = (short)f2bf(xa.x); a[1] = (short)f2bf(xa.y);
        a[2] = (short)f2bf(xa.z); a[3] = (short)f2bf(xa.w);
        a[4] = (short)f2bf(xb.x); a[5] = (short)f2bf(xb.y);
        a[6] = (short)f2bf(xb.z); a[7] = (short)f2bf(xb.w);
#pragma unroll
        for (int nt = 0; nt < 4; ++nt) {
            short8 b = wv[(kiter * 4 + nt) * 64 + lane];
            acc[nt] = __builtin_amdgcn_mfma_f32_16x16x32_bf16(a, b, acc[nt], 0, 0, 0);
        }
    }

    float di[4];
#pragma unroll
    for (int r = 0; r < 4; ++r) {
        int orow = rowbase + quad * 4 + r;
        di[r] = (orow < N_NODES) ? dinv[orow] : 0.f;
    }

#pragma unroll
    for (int nt = 0; nt < 4; ++nt) {
#pragma unroll
        for (int r = 0; r < 4; ++r) {
            int orow = rowbase + quad * 4 + r;
            if (orow < N_NODES) {
                int ocol = nt * 16 + m;
                h[(size_t)orow * HID + ocol] = f2bf(di[r] * acc[nt][r]);
            }
        }
    }
}

// ---------- cooperative fused layer-1: src-range phased gather (L2-tiled) ----------
// 391 blocks x 512 thr; block owns 256 dsts; acc[256][64] f32 in LDS (64 KB).
// Phase p: all blocks aggregate edges with src in [p*25K,(p+1)*25K) -> 3.2 MB h-tile
// stays L2-resident; grid.sync() between phases (pacing only — no cross-block deps).
__launch_bounds__(512, 4)
__global__ void fused1_coop(const int* __restrict__ rp4, const int2* __restrict__ ebuf,
                            const unsigned short* __restrict__ h,
                            const float* __restrict__ dinv, const float* __restrict__ b1,
                            const float* __restrict__ W2, float* __restrict__ z) {
    __shared__ float accs[256][64];   // exactly 64 KB
    cg::grid_group grid = cg::this_grid();

    int t = threadIdx.x;
    int lane = t & 63;
    int wave = t >> 6;            // 0..7
    int f = lane & 15;
    int g = lane >> 4;
    int d0 = blockIdx.x * 256;

    for (int i = t; i < 256 * 64; i += 512) ((float*)accs)[i] = 0.f;
    __syncthreads();

    const uint2* h64 = (const uint2*)h;

    for (int p = 0; p < 4; ++p) {
        for (int dstloc = wave; dstloc < 256; dstloc += 8) {
            int d = d0 + dstloc;
            if (d >= N_NODES) break;
            int start = rp4[4 * d + p];
            int end   = rp4[4 * d + p + 1];

            float4 acc = make_float4(0.f, 0.f, 0.f, 0.f);
            for (int base = start; base < end; base += 64) {
                int n = end - base; if (n > 64) n = 64;
                int2 e = (lane < n) ? ebuf[base + lane] : make_int2(0, 0);
                int j = 0;
                for (; j + 16 <= n; j += 16) {
                    uint2 hp[4]; float w[4];
#pragma unroll
                    for (int u = 0; u < 4; ++u) {
                        int idx = j + u * 4 + g;
                        int s = __shfl(e.x, idx);
                        w[u] = __int_as_float(__shfl(e.y, idx));
                        hp[u] = h64[(size_t)s * 16 + f];
                    }
#pragma unroll
                    for (int u = 0; u < 4; ++u) {
                        acc.x = fmaf(w[u], bfl(hp[u].x), acc.x);
                        acc.y = fmaf(w[u], bfh(hp[u].x), acc.y);
                        acc.z = fmaf(w[u], bfl(hp[u].y), acc.z);
                        acc.w = fmaf(w[u], bfh(hp[u].y), acc.w);
                    }
                }
                for (; j + 4 <= n; j += 4) {
                    int idx = j + g;
                    int s = __shfl(e.x, idx);
                    float w = __int_as_float(__shfl(e.y, idx));
                    uint2 hp = h64[(size_t)s * 16 + f];
                    acc.x = fmaf(w, bfl(hp.x), acc.x);
                    acc.y = fmaf(w, bfh(hp.x), acc.y);
                    acc.z = fmaf(w, bfl(hp.y), acc.z);
                    acc.w = fmaf(w, bfh(hp.y), acc.w);
                }
                int rem = n - j;
                if (rem > 0) {
                    int idx = j + (g < rem ? g : 0);
                    int s = __shfl(e.x, idx);
                    float w = __int_as_float(__shfl(e.y, idx));
                    if (g < rem) {
                        uint2 hp = h64[(size_t)s * 16 + f];
                        acc.x = fmaf(w, bfl(hp.x), acc.x);
                        acc.y = fmaf(w, bfh(hp.x), acc.y);
                        acc.z = fmaf(w, bfl(hp.y), acc.z);
                        acc.w = fmaf(w, bfh(hp.y), acc.w);
                    }
                }
            }

            acc.x += __shfl_down(acc.x, 32); acc.y += __shfl_down(acc.y, 32);
            acc.z += __shfl_down(acc.z, 32); acc.w += __shfl_down(acc.w, 32);
            acc.x += __shfl_down(acc.x, 16); acc.y += __shfl_down(acc.y, 16);
            acc.z += __shfl_down(acc.z, 16); acc.w += __shfl_down(acc.w, 16);

            if (g == 0) {
                float4* ap = (float4*)&accs[dstloc][4 * f];
                float4 cur = *ap;
                cur.x += acc.x; cur.y += acc.y; cur.z += acc.z; cur.w += acc.w;
                *ap = cur;
            }
        }
        if (p < 3) grid.sync();
    }
    __syncthreads();

    // epilogue: 16-lane groups, 4 dsts per wave iteration
    for (int dstloc = wave * 4 + g; dstloc < 256; dstloc += 32) {
        int d = d0 + dstloc;
        if (d < N_NODES) {
            float4 a = *(float4*)&accs[dstloc][4 * f];
            float di = dinv[d];
            uint2 hd = h64[(size_t)d * 16 + f];
            float4 b = *(const float4*)&b1[4 * f];
            float4 w2 = *(const float4*)&W2[4 * f];

            float v0 = di * (a.x + bfl(hd.x)) + b.x;
            float v1 = di * (a.y + bfh(hd.x)) + b.y;
            float v2 = di * (a.z + bfl(hd.y)) + b.z;
            float v3 = di * (a.w + bfh(hd.y)) + b.w;
            v0 = (v0 > 0.f) ? v0 : (__expf(v0) - 1.f);
            v1 = (v1 > 0.f) ? v1 : (__expf(v1) - 1.f);
            v2 = (v2 > 0.f) ? v2 : (__expf(v2) - 1.f);
            v3 = (v3 > 0.f) ? v3 : (__expf(v3) - 1.f);

            float pz = v0 * w2.x + v1 * w2.y + v2 * w2.z + v3 * w2.w;
            pz += __shfl_down(pz, 8);
            pz += __shfl_down(pz, 4);
            pz += __shfl_down(pz, 2);
            pz += __shfl_down(pz, 1);
            if (f == 0) z[d] = di * pz;   // z' = dinv[d] * z
        }
    }
}

// ---------- fallback fused layer-1 (quartered, rp4-based full runs) ----------
__launch_bounds__(256)
__global__ void fused1_kernel(const int* __restrict__ rp4, const int2* __restrict__ ebuf,
                              const unsigned short* __restrict__ h,
                              const float* __restrict__ dinv, const float* __restrict__ b1,
                              const float* __restrict__ W2, float* __restrict__ z, int dbase) {
    int lane = threadIdx.x & 63;
    int d = dbase + ((blockIdx.x * blockDim.x + threadIdx.x) >> 6);
    if (d >= N_NODES || d >= dbase + NQ) return;

    int start = rp4[4 * d];
    int end = rp4[4 * d + 4];
    int f = lane & 15;
    int g = lane >> 4;

    const uint2* h64 = (const uint2*)h;

    float4 acc = make_float4(0.f, 0.f, 0.f, 0.f);

    for (int base = start; base < end; base += 64) {
        int n = end - base; if (n > 64) n = 64;
        int2 e = (lane < n) ? ebuf[base + lane] : make_int2(0, 0);
        int j = 0;
        for (; j + 16 <= n; j += 16) {
            uint2 hp[4]; float w[4];
#pragma unroll
            for (int u = 0; u < 4; ++u) {
                int idx = j + u * 4 + g;
                int s = __shfl(e.x, idx);
                w[u] = __int_as_float(__shfl(e.y, idx));
                hp[u] = h64[(size_t)s * 16 + f];
            }
#pragma unroll
            for (int u = 0; u < 4; ++u) {
                acc.x = fmaf(w[u], bfl(hp[u].x), acc.x);
                acc.y = fmaf(w[u], bfh(hp[u].x), acc.y);
                acc.z = fmaf(w[u], bfl(hp[u].y), acc.z);
                acc.w = fmaf(w[u], bfh(hp[u].y), acc.w);
            }
        }
        for (; j + 4 <= n; j += 4) {
            int idx = j + g;
            int s = __shfl(e.x, idx);
            float w = __int_as_float(__shfl(e.y, idx));
            uint2 hp = h64[(size_t)s * 16 + f];
            acc.x = fmaf(w, bfl(hp.x), acc.x);
            acc.y = fmaf(w, bfh(hp.x), acc.y);
            acc.z = fmaf(w, bfl(hp.y), acc.z);
            acc.w = fmaf(w, bfh(hp.y), acc.w);
        }
        int rem = n - j;
        if (rem > 0) {
            int idx = j + (g < rem ? g : 0);
            int s = __shfl(e.x, idx);
            float w = __int_as_float(__shfl(e.y, idx));
            if (g < rem) {
                uint2 hp = h64[(size_t)s * 16 + f];
                acc.x = fmaf(w, bfl(hp.x), acc.x);
                acc.y = fmaf(w, bfh(hp.x), acc.y);
                acc.z = fmaf(w, bfl(hp.y), acc.z);
                acc.w = fmaf(w, bfh(hp.y), acc.w);
            }
        }
    }

    acc.x += __shfl_down(acc.x, 32); acc.y += __shfl_down(acc.y, 32);
    acc.z += __shfl_down(acc.z, 32); acc.w += __shfl_down(acc.w, 32);
    acc.x += __shfl_down(acc.x, 16); acc.y += __shfl_down(acc.y, 16);
    acc.z += __shfl_down(acc.z, 16); acc.w += __shfl_down(acc.w, 16);

    float di = dinv[d];
    uint2 hd = h64[(size_t)d * 16 + f];
    float4 b = *(const float4*)&b1[4 * f];
    float4 w2 = *(const float4*)&W2[4 * f];

    float v0 = di * (acc.x + bfl(hd.x)) + b.x;
    float v1 = di * (acc.y + bfh(hd.x)) + b.y;
    float v2 = di * (acc.z + bfl(hd.y)) + b.z;
    float v3 = di * (acc.w + bfh(hd.y)) + b.w;
    v0 = (v0 > 0.f) ? v0 : (__expf(v0) - 1.f);
    v1 = (v1 > 0.f) ? v1 : (__expf(v1) - 1.f);
    v2 = (v2 > 0.f) ? v2 : (__expf(v2) - 1.f);
    v3 = (v3 > 0.f) ? v3 : (__expf(v3) - 1.f);

    float p = v0 * w2.x + v1 * w2.y + v2 * w2.z + v3 * w2.w;
    p += __shfl_down(p, 8);
    p += __shfl_down(p, 4);
    p += __shfl_down(p, 2);
    p += __shfl_down(p, 1);
    if (lane == 0) z[d] = di * p;
}

// ---------- fused layer-2 aggregation + self-loop + bias + sigmoid ----------
__launch_bounds__(256)
__global__ void fused2_kernel(const int* __restrict__ rp4, const int2* __restrict__ ebuf,
                              const float* __restrict__ z, const float* __restrict__ dinv,
                              const float* __restrict__ b2, float* __restrict__ out) {
    int lane = threadIdx.x & 63;
    int d = (blockIdx.x * blockDim.x + threadIdx.x) >> 6;
    if (d >= N_NODES) return;

    int start = rp4[4 * d];
    int end = rp4[4 * d + 4];

    float acc = 0.0f;
    for (int i = start + lane; i < end; i += 64) {
        int2 e = ebuf[i];
        acc = fmaf(__int_as_float(e.y), z[e.x], acc);
    }
#pragma unroll
    for (int off = 32; off > 0; off >>= 1) acc += __shfl_down(acc, off);

    if (lane == 0) {
        float di = dinv[d];
        float v = di * (acc + z[d]) + b2[0];
        out[d] = 1.0f / (1.0f + __expf(-v));
    }
}

extern "C" void kernel_launch(void* const* d_in, const int* in_sizes, int n_in,
                              void* d_out, int out_size, void* d_ws, size_t ws_size,
                              hipStream_t stream) {
    const float* x  = (const float*)d_in[0];
    const int*   ei = (const int*)d_in[1];
    const float* ew = (const float*)d_in[2];
    const float* W1 = (const float*)d_in[3];
    const float* b1 = (const float*)d_in[4];
    const float* W2 = (const float*)d_in[5];
    const float* b2 = (const float*)d_in[6];
    float* out = (float*)d_out;

    char* ws = (char*)d_ws;
    unsigned int* blkhist = (unsigned int*)ws;                  ws += (size_t)NP1 * NBUCK * 4;
    unsigned int* blkbase = (unsigned int*)ws;                  ws += (size_t)NBUCK * NP1 * 4;
    unsigned int* total   = (unsigned int*)ws;                  ws += (size_t)NBUCK * 4;
    unsigned int* base    = (unsigned int*)ws;                  ws += (size_t)(NBUCK + 1) * 4;
    float* dinv    = (float*)ws;                                ws += (size_t)N_NODES * 4;
    int*   rp4     = (int*)ws;                                  ws += (size_t)(4 * N_NODES + 2) * 4;
    int2*  pbuf    = (int2*)ws;                                 ws += (size_t)N_EDGES * 8;
    int2*  ebuf    = (int2*)ws;                                 ws += (size_t)N_EDGES * 8;
    unsigned short* h = (unsigned short*)ws;                    ws += (size_t)N_NODES * HID * 2;
    unsigned short* wsw = (unsigned short*)ws;                  ws += (size_t)NF * HID * 2;
    float* z       = (float*)ws;                                ws += (size_t)N_NODES * 4;

    p1count<<<NP1, 256, 0, stream>>>(ei, blkhist, W1, wsw);
    bktA<<<NBUCK, 256, 0, stream>>>(blkhist, total);
    bktC<<<NBUCK, 256, 0, stream>>>(blkhist, total, blkbase, base);
    p1scatter<<<NP1, 256, 0, stream>>>(ei, ew, blkhist, blkbase, pbuf);
    p2ab<<<NBUCK, 256, 0, stream>>>(pbuf, base, dinv, rp4, ebuf);

    gemm1_mfma<<<(N_NODES + 63) / 64, 256, 0, stream>>>(x, wsw, dinv, h);

    // cooperative src-phased fused1; runtime fallback to quartered version
    {
        const int* rp4c = rp4; const int2* ebufc = ebuf;
        const unsigned short* hc = h; const float* dinvc = dinv;
        const float* b1c = b1; const float* W2c = W2; float* zc = z;
        void* args[] = {(void*)&rp4c, (void*)&ebufc, (void*)&hc, (void*)&dinvc,
                        (void*)&b1c, (void*)&W2c, (void*)&zc};
        hipError_t cerr = hipLaunchCooperativeKernel((const void*)fused1_coop,
                                                     dim3(NBB), dim3(512), args, 0, stream);
        if (cerr != hipSuccess) {
            int qgrid = (NQ * 64) / 256;
            fused1_kernel<<<qgrid, 256, 0, stream>>>(rp4, ebuf, h, dinv, b1, W2, z, 0);
            fused1_kernel<<<qgrid, 256, 0, stream>>>(rp4, ebuf, h, dinv, b1, W2, z, NQ);
            fused1_kernel<<<qgrid, 256, 0, stream>>>(rp4, ebuf, h, dinv, b1, W2, z, 2 * NQ);
            fused1_kernel<<<qgrid, 256, 0, stream>>>(rp4, ebuf, h, dinv, b1, W2, z, 3 * NQ);
        }
    }

    int grid = (N_NODES * 64 + 255) / 256;
    fused2_kernel<<<grid, 256, 0, stream>>>(rp4, ebuf, z, dinv, b2, out);
}

// Round 11
// 439.880 us; speedup vs baseline: 1.5453x; 1.5453x over previous
//
#include <hip/hip_runtime.h>

#define N_NODES 100000
#define N_EDGES 3200000
#define NF 256
#define HID 64
#define BSHIFT 7
#define NBUCK 782                       // ceil(100000 / 128)
#define NP1 512                         // phase-1 partition blocks
#define CHUNKE (N_EDGES / NP1)          // 6250 exactly (even)
#define MAXB 5120                       // p2ab LDS sort capacity per bucket
#define NQ 25000                        // src-partition width (h tile = 3.2 MB < 4 MB L2)

typedef short short8 __attribute__((ext_vector_type(8)));
typedef float f32x4 __attribute__((ext_vector_type(4)));

__device__ __forceinline__ unsigned short f2bf(float v) {
    unsigned int u = __float_as_uint(v);
    u += 0x7FFFu + ((u >> 16) & 1u);
    return (unsigned short)(u >> 16);
}
__device__ __forceinline__ float bfl(unsigned int p) { return __uint_as_float((p & 0xFFFFu) << 16); }
__device__ __forceinline__ float bfh(unsigned int p) { return __uint_as_float(p & 0xFFFF0000u); }

// ---------- 1a: per-block LDS histogram + folded one-time W1 swizzle ----------
__launch_bounds__(256)
__global__ void p1count(const int* __restrict__ ei, unsigned int* __restrict__ blkhist,
                        const float* __restrict__ W, unsigned short* __restrict__ wsw) {
    __shared__ unsigned int hist[NBUCK];
    if (blockIdx.x < 64) {
        int idx = blockIdx.x * 256 + threadIdx.x;
        int j = idx & 7;
        int lane = (idx >> 3) & 63;
        int ntile = (idx >> 9) & 3;
        int kiter = idx >> 11;
        int k = kiter * 32 + (lane >> 4) * 8 + j;
        int n = ntile * 16 + (lane & 15);
        wsw[idx] = f2bf(W[k * HID + n]);
    }
    for (int i = threadIdx.x; i < NBUCK; i += 256) hist[i] = 0;
    __syncthreads();
    int lo = blockIdx.x * CHUNKE;
    int hi = lo + CHUNKE;
    for (int e = lo + 2 * threadIdx.x; e < hi; e += 512) {
        int2 d2 = *(const int2*)&ei[N_EDGES + e];
        atomicAdd(&hist[((unsigned)d2.x) >> BSHIFT], 1u);
        atomicAdd(&hist[((unsigned)d2.y) >> BSHIFT], 1u);
    }
    __syncthreads();
    unsigned int* row = blkhist + (size_t)blockIdx.x * NBUCK;
    for (int i = threadIdx.x; i < NBUCK; i += 256) row[i] = hist[i];
}

// ---------- 1b: column reduce -> bucket_total[bucket] ----------
__launch_bounds__(256)
__global__ void bktA(const unsigned int* __restrict__ blkhist, unsigned int* __restrict__ total) {
    __shared__ unsigned int sh[256];
    int i = blockIdx.x;              // bucket
    int t = threadIdx.x;
    unsigned s = 0;
    for (int b = t; b < NP1; b += 256) s += blkhist[(size_t)b * NBUCK + i];
    sh[t] = s;
    __syncthreads();
    for (int off = 128; off > 0; off >>= 1) {
        if (t < off) sh[t] += sh[t + off];
        __syncthreads();
    }
    if (t == 0) total[i] = sh[0];
}

// ---------- 1cd merged: base_i reduction + per-bucket scan across blocks ----------
__launch_bounds__(256)
__global__ void bktC(const unsigned int* __restrict__ blkhist, const unsigned int* __restrict__ total,
                     unsigned int* __restrict__ blkbase, unsigned int* __restrict__ base) {
    __shared__ unsigned int sh[256];
    int i = blockIdx.x;              // bucket
    int t = threadIdx.x;

    unsigned bs = 0;
    for (int j = t; j < i; j += 256) bs += total[j];
    sh[t] = bs;
    __syncthreads();
    for (int off = 128; off > 0; off >>= 1) {
        if (t < off) sh[t] += sh[t + off];
        __syncthreads();
    }
    unsigned base_i = sh[0];
    __syncthreads();
    if (t == 0) {
        base[i] = base_i;
        if (i == 0) base[NBUCK] = N_EDGES;
    }

    unsigned c[2];
    unsigned s = 0;
#pragma unroll
    for (int j = 0; j < 2; ++j) {
        c[j] = blkhist[(size_t)(2 * t + j) * NBUCK + i];
        s += c[j];
    }
    sh[t] = s;
    __syncthreads();
    for (int off = 1; off < 256; off <<= 1) {
        unsigned a = (t >= off) ? sh[t - off] : 0;
        __syncthreads();
        sh[t] += a;
        __syncthreads();
    }
    unsigned run = base_i + sh[t] - s;
    unsigned int* orow = blkbase + (size_t)i * NP1 + 2 * t;
    orow[0] = run; run += c[0];
    orow[1] = run;
}

// ---------- 1e: staged scatter — LDS counting sort, then coalesced run write-out ----------
__launch_bounds__(256)
__global__ void p1scatter(const int* __restrict__ ei, const float* __restrict__ ew,
                          const unsigned int* __restrict__ blkhist,
                          const unsigned int* __restrict__ blkbase, int2* __restrict__ pbuf) {
    __shared__ int2 sorted[CHUNKE];           // 50000 B
    __shared__ unsigned int loff[NBUCK + 2];
    __shared__ unsigned int cur[NBUCK];
    __shared__ unsigned int sh[256];

    int t = threadIdx.x;
    int b = blockIdx.x;

    unsigned u[4];
    unsigned s = 0;
#pragma unroll
    for (int j = 0; j < 4; ++j) {
        int idx = 4 * t + j;
        u[j] = (idx < NBUCK) ? blkhist[(size_t)b * NBUCK + idx] : 0u;
        s += u[j];
    }
    sh[t] = s;
    __syncthreads();
    for (int off = 1; off < 256; off <<= 1) {
        unsigned a = (t >= off) ? sh[t - off] : 0;
        __syncthreads();
        sh[t] += a;
        __syncthreads();
    }
    unsigned run = sh[t] - s;
#pragma unroll
    for (int j = 0; j < 4; ++j) {
        int idx = 4 * t + j;
        if (idx <= NBUCK) loff[idx] = run;
        run += u[j];
        if (idx < NBUCK) cur[idx] = 0;
    }
    __syncthreads();

    int lo = b * CHUNKE;
    int hi = lo + CHUNKE;
    for (int e = lo + 2 * t; e < hi; e += 512) {
        int2 s2 = *(const int2*)&ei[e];
        int2 d2 = *(const int2*)&ei[N_EDGES + e];
        float2 w2 = *(const float2*)&ew[e];
        unsigned k0 = ((unsigned)d2.x) >> BSHIFT;
        unsigned r0 = atomicAdd(&cur[k0], 1u);
        sorted[loff[k0] + r0] = make_int2(s2.x | (int)(((unsigned)d2.x & 127u) << 17), __float_as_int(w2.x));
        unsigned k1 = ((unsigned)d2.y) >> BSHIFT;
        unsigned r1 = atomicAdd(&cur[k1], 1u);
        sorted[loff[k1] + r1] = make_int2(s2.y | (int)(((unsigned)d2.y & 127u) << 17), __float_as_int(w2.y));
    }
    __syncthreads();

    int lane = t & 63;
    int wave = t >> 6;
    int q = lane >> 3;
    int r8 = lane & 7;
    for (int k0 = wave * 8; k0 < NBUCK; k0 += 32) {
        int k = k0 + q;
        if (k < NBUCK) {
            unsigned off = loff[k];
            int n = (int)(loff[k + 1] - off);
            unsigned gb = blkbase[(size_t)k * NP1 + b];
            for (int i = r8; i < n; i += 8)
                pbuf[gb + i] = sorted[off + i];
        }
    }
}

// ---------- phase 2: 512-bin (dst_low7, src/25000) sort + deg/dinv + rp4 CSR ----------
__launch_bounds__(256)
__global__ void p2ab(const int2* __restrict__ pbuf, const unsigned int* __restrict__ base,
                     float* __restrict__ dinv, int* __restrict__ rp4, int2* __restrict__ ebuf) {
    __shared__ int lcnt[512];
    __shared__ float ldeg[128];
    __shared__ int sc[256];
    __shared__ int loff[512];
    __shared__ unsigned int lcur[512];
    __shared__ int2 sorted[MAXB];    // 40 KB

    int t = threadIdx.x;
    int bkt = blockIdx.x;
    unsigned b0 = base[bkt], bh = base[bkt + 1];
    int nb = (int)(bh - b0);
    int d0 = bkt << BSHIFT;
    int nd = N_NODES - d0; if (nd > 128) nd = 128;

    lcnt[t] = 0; lcnt[t + 256] = 0;
    lcur[t] = 0; lcur[t + 256] = 0;
    if (t < 128) ldeg[t] = 0.f;
    __syncthreads();

    for (int i = t; i < nb; i += 256) {
        int2 e = pbuf[b0 + i];
        int dl = (e.x >> 17) & 127;
        unsigned src = (unsigned)(e.x & 0x1FFFF);
        int key = (dl << 2) | (int)(src / (unsigned)NQ);
        atomicAdd(&lcnt[key], 1);
        atomicAdd(&ldeg[dl], __int_as_float(e.y));
    }
    __syncthreads();

    int c0 = lcnt[2 * t], c1 = lcnt[2 * t + 1];
    int s = c0 + c1;
    sc[t] = s;
    __syncthreads();
    for (int off = 1; off < 256; off <<= 1) {
        int a = (t >= off) ? sc[t - off] : 0;
        __syncthreads();
        sc[t] += a;
        __syncthreads();
    }
    int excl = sc[t] - s;
    loff[2 * t] = excl;
    loff[2 * t + 1] = excl + c0;
    __syncthreads();

    if ((t >> 2) < nd) rp4[4 * d0 + t] = (int)(b0 + (unsigned)loff[t]);
    {
        int k2 = t + 256;
        if ((k2 >> 2) < nd) rp4[4 * d0 + k2] = (int)(b0 + (unsigned)loff[k2]);
    }
    if (t < 128 && t < nd) dinv[d0 + t] = rsqrtf(ldeg[t] + 1.0f);
    if (bkt == NBUCK - 1 && t == 0) rp4[4 * N_NODES] = N_EDGES;
    __syncthreads();

    if (nb <= MAXB) {
        for (int i = t; i < nb; i += 256) {
            int2 e = pbuf[b0 + i];
            int sidx = e.x & 0x1FFFF;
            int dl = (e.x >> 17) & 127;
            int key = (dl << 2) | (int)((unsigned)sidx / (unsigned)NQ);
            unsigned r = atomicAdd(&lcur[key], 1u);
            sorted[loff[key] + (int)r] = make_int2(sidx, e.y);
        }
        __syncthreads();
        for (int i = t; i < nb; i += 256) ebuf[b0 + i] = sorted[i];
    } else {
        for (int i = t; i < nb; i += 256) {
            int2 e = pbuf[b0 + i];
            int sidx = e.x & 0x1FFFF;
            int dl = (e.x >> 17) & 127;
            int key = (dl << 2) | (int)((unsigned)sidx / (unsigned)NQ);
            unsigned r = atomicAdd(&lcur[key], 1u);
            ebuf[b0 + loff[key] + r] = make_int2(sidx, e.y);
        }
    }
}

// ---------- h' = dinv[row] * (x @ W1) via MFMA ----------
__launch_bounds__(256)
__global__ void gemm1_mfma(const float* __restrict__ x, const unsigned short* __restrict__ wsw,
                           const float* __restrict__ dinv, unsigned short* __restrict__ h) {
    int t = threadIdx.x;
    int lane = t & 63;
    int wave = t >> 6;
    int m = lane & 15;
    int quad = lane >> 4;
    int rowbase = blockIdx.x * 64 + wave * 16;

    int row = rowbase + m;
    if (row >= N_NODES) row = N_NODES - 1;

    const short8* wv = (const short8*)wsw;

    f32x4 acc[4] = {{0.f,0.f,0.f,0.f},{0.f,0.f,0.f,0.f},{0.f,0.f,0.f,0.f},{0.f,0.f,0.f,0.f}};

    const float* xrow = x + (size_t)row * NF;
#pragma unroll
    for (int kiter = 0; kiter < 8; ++kiter) {
        int k0 = kiter * 32 + quad * 8;
        float4 xa = *(const float4*)&xrow[k0];
        float4 xb = *(const float4*)&xrow[k0 + 4];
        short8 a;
        a[0] = (short)f2bf(xa.x); a[1] = (short)f2bf(xa.y);
        a[2] = (short)f2bf(xa.z); a[3] = (short)f2bf(xa.w);
        a[4] = (short)f2bf(xb.x); a[5] = (short)f2bf(xb.y);
        a[6] = (short)f2bf(xb.z); a[7] = (short)f2bf(xb.w);
#pragma unroll
        for (int nt = 0; nt < 4; ++nt) {
            short8 b = wv[(kiter * 4 + nt) * 64 + lane];
            acc[nt] = __builtin_amdgcn_mfma_f32_16x16x32_bf16(a, b, acc[nt], 0, 0, 0);
        }
    }

    float di[4];
#pragma unroll
    for (int r = 0; r < 4; ++r) {
        int orow = rowbase + quad * 4 + r;
        di[r] = (orow < N_NODES) ? dinv[orow] : 0.f;
    }

#pragma unroll
    for (int nt = 0; nt < 4; ++nt) {
#pragma unroll
        for (int r = 0; r < 4; ++r) {
            int orow = rowbase + quad * 4 + r;
            if (orow < N_NODES) {
                int ocol = nt * 16 + m;
                h[(size_t)orow * HID + ocol] = f2bf(di[r] * acc[nt][r]);
            }
        }
    }
}

// ---------- fused layer-1, src-phased: all dsts, one src-range per launch ----------
// Launch p gathers only edges with src in [p*NQ,(p+1)*NQ) -> h-tile (3.2 MB) is
// L2-resident for the whole dispatch. Partials accumulate in accb (f32, 25.6 MB);
// phase 3 adds self-loop + bias + ELU + @W2 epilogue and writes z.
__launch_bounds__(256)
__global__ void fused1_phase(const int* __restrict__ rp4, const int2* __restrict__ ebuf,
                             const unsigned short* __restrict__ h,
                             const float* __restrict__ dinv, const float* __restrict__ b1,
                             const float* __restrict__ W2, float* __restrict__ accb,
                             float* __restrict__ z, int phase) {
    int lane = threadIdx.x & 63;
    int d = (blockIdx.x * blockDim.x + threadIdx.x) >> 6;
    if (d >= N_NODES) return;

    int start = rp4[4 * d + phase];
    int end   = rp4[4 * d + phase + 1];
    int f = lane & 15;
    int g = lane >> 4;

    const uint2* h64 = (const uint2*)h;

    float4 acc = make_float4(0.f, 0.f, 0.f, 0.f);

    for (int base = start; base < end; base += 64) {
        int n = end - base; if (n > 64) n = 64;
        int2 e = (lane < n) ? ebuf[base + lane] : make_int2(0, 0);
        int j = 0;
        for (; j + 16 <= n; j += 16) {
            uint2 hp[4]; float w[4];
#pragma unroll
            for (int u = 0; u < 4; ++u) {
                int idx = j + u * 4 + g;
                int s = __shfl(e.x, idx);
                w[u] = __int_as_float(__shfl(e.y, idx));
                hp[u] = h64[(size_t)s * 16 + f];
            }
#pragma unroll
            for (int u = 0; u < 4; ++u) {
                acc.x = fmaf(w[u], bfl(hp[u].x), acc.x);
                acc.y = fmaf(w[u], bfh(hp[u].x), acc.y);
                acc.z = fmaf(w[u], bfl(hp[u].y), acc.z);
                acc.w = fmaf(w[u], bfh(hp[u].y), acc.w);
            }
        }
        for (; j + 4 <= n; j += 4) {
            int idx = j + g;
            int s = __shfl(e.x, idx);
            float w = __int_as_float(__shfl(e.y, idx));
            uint2 hp = h64[(size_t)s * 16 + f];
            acc.x = fmaf(w, bfl(hp.x), acc.x);
            acc.y = fmaf(w, bfh(hp.x), acc.y);
            acc.z = fmaf(w, bfl(hp.y), acc.z);
            acc.w = fmaf(w, bfh(hp.y), acc.w);
        }
        int rem = n - j;
        if (rem > 0) {
            int idx = j + (g < rem ? g : 0);
            int s = __shfl(e.x, idx);
            float w = __int_as_float(__shfl(e.y, idx));
            if (g < rem) {
                uint2 hp = h64[(size_t)s * 16 + f];
                acc.x = fmaf(w, bfl(hp.x), acc.x);
                acc.y = fmaf(w, bfh(hp.x), acc.y);
                acc.z = fmaf(w, bfl(hp.y), acc.z);
                acc.w = fmaf(w, bfh(hp.y), acc.w);
            }
        }
    }

    acc.x += __shfl_down(acc.x, 32); acc.y += __shfl_down(acc.y, 32);
    acc.z += __shfl_down(acc.z, 32); acc.w += __shfl_down(acc.w, 32);
    acc.x += __shfl_down(acc.x, 16); acc.y += __shfl_down(acc.y, 16);
    acc.z += __shfl_down(acc.z, 16); acc.w += __shfl_down(acc.w, 16);
    // lanes 0..15 (g==0) hold the 4-feature partial sums

    if (phase < 3) {
        if (g == 0) {
            float4* ap = (float4*)&accb[(size_t)d * 64 + 4 * f];
            if (phase == 0) {
                *ap = acc;
            } else {
                float4 o = *ap;
                o.x += acc.x; o.y += acc.y; o.z += acc.z; o.w += acc.w;
                *ap = o;
            }
        }
        return;
    }

    if (g != 0) return;
    float4 o = *(const float4*)&accb[(size_t)d * 64 + 4 * f];
    acc.x += o.x; acc.y += o.y; acc.z += o.z; acc.w += o.w;

    float di = dinv[d];
    uint2 hd = h64[(size_t)d * 16 + f];   // h' already carries dinv[d]
    float4 b = *(const float4*)&b1[4 * f];
    float4 w2 = *(const float4*)&W2[4 * f];

    float v0 = di * (acc.x + bfl(hd.x)) + b.x;
    float v1 = di * (acc.y + bfh(hd.x)) + b.y;
    float v2 = di * (acc.z + bfl(hd.y)) + b.z;
    float v3 = di * (acc.w + bfh(hd.y)) + b.w;
    v0 = (v0 > 0.f) ? v0 : (__expf(v0) - 1.f);
    v1 = (v1 > 0.f) ? v1 : (__expf(v1) - 1.f);
    v2 = (v2 > 0.f) ? v2 : (__expf(v2) - 1.f);
    v3 = (v3 > 0.f) ? v3 : (__expf(v3) - 1.f);

    float p = v0 * w2.x + v1 * w2.y + v2 * w2.z + v3 * w2.w;
    p += __shfl_down(p, 8);
    p += __shfl_down(p, 4);
    p += __shfl_down(p, 2);
    p += __shfl_down(p, 1);
    if (f == 0) z[d] = di * p;        // z' = dinv[d] * z
}

// ---------- fused layer-2 aggregation + self-loop + bias + sigmoid ----------
__launch_bounds__(256)
__global__ void fused2_kernel(const int* __restrict__ rp4, const int2* __restrict__ ebuf,
                              const float* __restrict__ z, const float* __restrict__ dinv,
                              const float* __restrict__ b2, float* __restrict__ out) {
    int lane = threadIdx.x & 63;
    int d = (blockIdx.x * blockDim.x + threadIdx.x) >> 6;
    if (d >= N_NODES) return;

    int start = rp4[4 * d];
    int end = rp4[4 * d + 4];

    float acc = 0.0f;
    for (int i = start + lane; i < end; i += 64) {
        int2 e = ebuf[i];
        acc = fmaf(__int_as_float(e.y), z[e.x], acc);
    }
#pragma unroll
    for (int off = 32; off > 0; off >>= 1) acc += __shfl_down(acc, off);

    if (lane == 0) {
        float di = dinv[d];
        float v = di * (acc + z[d]) + b2[0];
        out[d] = 1.0f / (1.0f + __expf(-v));
    }
}

extern "C" void kernel_launch(void* const* d_in, const int* in_sizes, int n_in,
                              void* d_out, int out_size, void* d_ws, size_t ws_size,
                              hipStream_t stream) {
    const float* x  = (const float*)d_in[0];
    const int*   ei = (const int*)d_in[1];
    const float* ew = (const float*)d_in[2];
    const float* W1 = (const float*)d_in[3];
    const float* b1 = (const float*)d_in[4];
    const float* W2 = (const float*)d_in[5];
    const float* b2 = (const float*)d_in[6];
    float* out = (float*)d_out;

    char* ws = (char*)d_ws;
    unsigned int* blkhist = (unsigned int*)ws;                  ws += (size_t)NP1 * NBUCK * 4;
    unsigned int* blkbase = (unsigned int*)ws;                  ws += (size_t)NBUCK * NP1 * 4;
    unsigned int* total   = (unsigned int*)ws;                  ws += (size_t)NBUCK * 4;
    unsigned int* base    = (unsigned int*)ws;                  ws += (size_t)(NBUCK + 1) * 4;
    float* dinv    = (float*)ws;                                ws += (size_t)N_NODES * 4;
    int*   rp4     = (int*)ws;                                  ws += (size_t)(4 * N_NODES + 2) * 4;
    int2*  pbuf    = (int2*)ws;                                 ws += (size_t)N_EDGES * 8;
    int2*  ebuf    = (int2*)ws;                                 ws += (size_t)N_EDGES * 8;
    unsigned short* h = (unsigned short*)ws;                    ws += (size_t)N_NODES * HID * 2;
    unsigned short* wsw = (unsigned short*)ws;                  ws += (size_t)NF * HID * 2;
    float* z       = (float*)ws;                                ws += (size_t)N_NODES * 4;
    float* accb    = (float*)ws;                                ws += (size_t)N_NODES * HID * 4;

    p1count<<<NP1, 256, 0, stream>>>(ei, blkhist, W1, wsw);
    bktA<<<NBUCK, 256, 0, stream>>>(blkhist, total);
    bktC<<<NBUCK, 256, 0, stream>>>(blkhist, total, blkbase, base);
    p1scatter<<<NP1, 256, 0, stream>>>(ei, ew, blkhist, blkbase, pbuf);
    p2ab<<<NBUCK, 256, 0, stream>>>(pbuf, base, dinv, rp4, ebuf);

    gemm1_mfma<<<(N_NODES + 63) / 64, 256, 0, stream>>>(x, wsw, dinv, h);

    int grid = (N_NODES * 64 + 255) / 256;   // 25000 blocks, 1 wave per dst
    fused1_phase<<<grid, 256, 0, stream>>>(rp4, ebuf, h, dinv, b1, W2, accb, z, 0);
    fused1_phase<<<grid, 256, 0, stream>>>(rp4, ebuf, h, dinv, b1, W2, accb, z, 1);
    fused1_phase<<<grid, 256, 0, stream>>>(rp4, ebuf, h, dinv, b1, W2, accb, z, 2);
    fused1_phase<<<grid, 256, 0, stream>>>(rp4, ebuf, h, dinv, b1, W2, accb, z, 3);

    fused2_kernel<<<grid, 256, 0, stream>>>(rp4, ebuf, z, dinv, b2, out);
}

// Round 12
// 369.831 us; speedup vs baseline: 1.8380x; 1.1894x over previous
//
#include <hip/hip_runtime.h>

#define N_NODES 100000
#define N_EDGES 3200000
#define NF 256
#define HID 64
#define BSHIFT 7
#define NBUCK 782                       // ceil(100000 / 128)
#define NP1 512                         // phase-1 partition blocks
#define CHUNKE (N_EDGES / NP1)          // 6250 exactly (even)
#define MAXB 5120                       // p2ab LDS sort capacity per bucket

typedef short short8 __attribute__((ext_vector_type(8)));
typedef float f32x4 __attribute__((ext_vector_type(4)));

__device__ __forceinline__ unsigned short f2bf(float v) {
    unsigned int u = __float_as_uint(v);
    u += 0x7FFFu + ((u >> 16) & 1u);
    return (unsigned short)(u >> 16);
}
__device__ __forceinline__ float bfl(unsigned int p) { return __uint_as_float((p & 0xFFFFu) << 16); }
__device__ __forceinline__ float bfh(unsigned int p) { return __uint_as_float(p & 0xFFFF0000u); }

// ---------- 1a: per-block LDS histogram + folded one-time W1 swizzle ----------
__launch_bounds__(256)
__global__ void p1count(const int* __restrict__ ei, unsigned int* __restrict__ blkhist,
                        const float* __restrict__ W, unsigned short* __restrict__ wsw) {
    __shared__ unsigned int hist[NBUCK];
    if (blockIdx.x < 64) {
        int idx = blockIdx.x * 256 + threadIdx.x;
        int j = idx & 7;
        int lane = (idx >> 3) & 63;
        int ntile = (idx >> 9) & 3;
        int kiter = idx >> 11;
        int k = kiter * 32 + (lane >> 4) * 8 + j;
        int n = ntile * 16 + (lane & 15);
        wsw[idx] = f2bf(W[k * HID + n]);
    }
    for (int i = threadIdx.x; i < NBUCK; i += 256) hist[i] = 0;
    __syncthreads();
    int lo = blockIdx.x * CHUNKE;
    int hi = lo + CHUNKE;
    for (int e = lo + 2 * threadIdx.x; e < hi; e += 512) {
        int2 d2 = *(const int2*)&ei[N_EDGES + e];
        atomicAdd(&hist[((unsigned)d2.x) >> BSHIFT], 1u);
        atomicAdd(&hist[((unsigned)d2.y) >> BSHIFT], 1u);
    }
    __syncthreads();
    unsigned int* row = blkhist + (size_t)blockIdx.x * NBUCK;
    for (int i = threadIdx.x; i < NBUCK; i += 256) row[i] = hist[i];
}

// ---------- 1b: column reduce -> bucket_total[bucket] ----------
__launch_bounds__(256)
__global__ void bktA(const unsigned int* __restrict__ blkhist, unsigned int* __restrict__ total) {
    __shared__ unsigned int sh[256];
    int i = blockIdx.x;              // bucket
    int t = threadIdx.x;
    unsigned s = 0;
    for (int b = t; b < NP1; b += 256) s += blkhist[(size_t)b * NBUCK + i];
    sh[t] = s;
    __syncthreads();
    for (int off = 128; off > 0; off >>= 1) {
        if (t < off) sh[t] += sh[t + off];
        __syncthreads();
    }
    if (t == 0) total[i] = sh[0];
}

// ---------- 1cd merged: base_i reduction + per-bucket scan across blocks ----------
__launch_bounds__(256)
__global__ void bktC(const unsigned int* __restrict__ blkhist, const unsigned int* __restrict__ total,
                     unsigned int* __restrict__ blkbase, unsigned int* __restrict__ base) {
    __shared__ unsigned int sh[256];
    int i = blockIdx.x;              // bucket
    int t = threadIdx.x;

    unsigned bs = 0;
    for (int j = t; j < i; j += 256) bs += total[j];
    sh[t] = bs;
    __syncthreads();
    for (int off = 128; off > 0; off >>= 1) {
        if (t < off) sh[t] += sh[t + off];
        __syncthreads();
    }
    unsigned base_i = sh[0];
    __syncthreads();
    if (t == 0) {
        base[i] = base_i;
        if (i == 0) base[NBUCK] = N_EDGES;
    }

    unsigned c[2];
    unsigned s = 0;
#pragma unroll
    for (int j = 0; j < 2; ++j) {
        c[j] = blkhist[(size_t)(2 * t + j) * NBUCK + i];
        s += c[j];
    }
    sh[t] = s;
    __syncthreads();
    for (int off = 1; off < 256; off <<= 1) {
        unsigned a = (t >= off) ? sh[t - off] : 0;
        __syncthreads();
        sh[t] += a;
        __syncthreads();
    }
    unsigned run = base_i + sh[t] - s;
    unsigned int* orow = blkbase + (size_t)i * NP1 + 2 * t;
    orow[0] = run; run += c[0];
    orow[1] = run;
}

// ---------- 1e: staged scatter — LDS counting sort, then coalesced run write-out ----------
__launch_bounds__(256)
__global__ void p1scatter(const int* __restrict__ ei, const float* __restrict__ ew,
                          const unsigned int* __restrict__ blkhist,
                          const unsigned int* __restrict__ blkbase, int2* __restrict__ pbuf) {
    __shared__ int2 sorted[CHUNKE];           // 50000 B
    __shared__ unsigned int loff[NBUCK + 2];
    __shared__ unsigned int cur[NBUCK];
    __shared__ unsigned int sh[256];

    int t = threadIdx.x;
    int b = blockIdx.x;

    unsigned u[4];
    unsigned s = 0;
#pragma unroll
    for (int j = 0; j < 4; ++j) {
        int idx = 4 * t + j;
        u[j] = (idx < NBUCK) ? blkhist[(size_t)b * NBUCK + idx] : 0u;
        s += u[j];
    }
    sh[t] = s;
    __syncthreads();
    for (int off = 1; off < 256; off <<= 1) {
        unsigned a = (t >= off) ? sh[t - off] : 0;
        __syncthreads();
        sh[t] += a;
        __syncthreads();
    }
    unsigned run = sh[t] - s;
#pragma unroll
    for (int j = 0; j < 4; ++j) {
        int idx = 4 * t + j;
        if (idx <= NBUCK) loff[idx] = run;
        run += u[j];
        if (idx < NBUCK) cur[idx] = 0;
    }
    __syncthreads();

    int lo = b * CHUNKE;
    int hi = lo + CHUNKE;
    for (int e = lo + 2 * t; e < hi; e += 512) {
        int2 s2 = *(const int2*)&ei[e];
        int2 d2 = *(const int2*)&ei[N_EDGES + e];
        float2 w2 = *(const float2*)&ew[e];
        unsigned k0 = ((unsigned)d2.x) >> BSHIFT;
        unsigned r0 = atomicAdd(&cur[k0], 1u);
        sorted[loff[k0] + r0] = make_int2(s2.x | (int)(((unsigned)d2.x & 127u) << 17), __float_as_int(w2.x));
        unsigned k1 = ((unsigned)d2.y) >> BSHIFT;
        unsigned r1 = atomicAdd(&cur[k1], 1u);
        sorted[loff[k1] + r1] = make_int2(s2.y | (int)(((unsigned)d2.y & 127u) << 17), __float_as_int(w2.y));
    }
    __syncthreads();

    int lane = t & 63;
    int wave = t >> 6;
    int q = lane >> 3;
    int r8 = lane & 7;
    for (int k0 = wave * 8; k0 < NBUCK; k0 += 32) {
        int k = k0 + q;
        if (k < NBUCK) {
            unsigned off = loff[k];
            int n = (int)(loff[k + 1] - off);
            unsigned gb = blkbase[(size_t)k * NP1 + b];
            for (int i = r8; i < n; i += 8)
                pbuf[gb + i] = sorted[off + i];
        }
    }
}

// ---------- phase 2 (merged): cnt + weighted deg + dinv + scan + LDS sort + coalesced CSR ----------
// ebuf stores RAW edge weight; dinv[s]/dinv[d] are folded into h' and z' downstream.
__launch_bounds__(256)
__global__ void p2ab(const int2* __restrict__ pbuf, const unsigned int* __restrict__ base,
                     float* __restrict__ dinv, int* __restrict__ row_ptr,
                     int2* __restrict__ ebuf) {
    __shared__ int lcnt[128];
    __shared__ float ldeg[128];
    __shared__ int sc[128];
    __shared__ int loff[128];
    __shared__ unsigned int lcur[128];
    __shared__ int2 sorted[MAXB];    // 40 KB

    int t = threadIdx.x;
    int bkt = blockIdx.x;
    unsigned b0 = base[bkt], bh = base[bkt + 1];
    int nb = (int)(bh - b0);
    int d0 = bkt << BSHIFT;
    int nd = N_NODES - d0; if (nd > 128) nd = 128;

    if (t < 128) { lcnt[t] = 0; ldeg[t] = 0.f; lcur[t] = 0; }
    __syncthreads();

    for (int i = t; i < nb; i += 256) {
        int2 e = pbuf[b0 + i];
        int dl = (e.x >> 17) & 127;
        atomicAdd(&lcnt[dl], 1);
        atomicAdd(&ldeg[dl], __int_as_float(e.y));
    }
    __syncthreads();

    int c = (t < 128) ? lcnt[t] : 0;
    if (t < 128) sc[t] = c;
    __syncthreads();
    for (int off = 1; off < 128; off <<= 1) {
        int a = (t < 128 && t >= off) ? sc[t - off] : 0;
        __syncthreads();
        if (t < 128) sc[t] += a;
        __syncthreads();
    }
    if (t < 128) {
        int excl = sc[t] - c;
        loff[t] = excl;
        if (t < nd) {
            row_ptr[d0 + t] = (int)(b0 + (unsigned)excl);
            dinv[d0 + t] = rsqrtf(ldeg[t] + 1.0f);
        }
    }
    if (bkt == NBUCK - 1 && t == 0) row_ptr[N_NODES] = N_EDGES;
    __syncthreads();

    if (nb <= MAXB) {
        for (int i = t; i < nb; i += 256) {
            int2 e = pbuf[b0 + i];
            int s = e.x & 0x1FFFF;
            int dl = (e.x >> 17) & 127;
            unsigned r = atomicAdd(&lcur[dl], 1u);
            sorted[loff[dl] + (int)r] = make_int2(s, e.y);
        }
        __syncthreads();
        for (int i = t; i < nb; i += 256) ebuf[b0 + i] = sorted[i];
    } else {
        for (int i = t; i < nb; i += 256) {
            int2 e = pbuf[b0 + i];
            int s = e.x & 0x1FFFF;
            int dl = (e.x >> 17) & 127;
            unsigned r = atomicAdd(&lcur[dl], 1u);
            ebuf[b0 + loff[dl] + r] = make_int2(s, e.y);
        }
    }
}

// ---------- h' = dinv[row] * (x @ W1) via MFMA ----------
__launch_bounds__(256)
__global__ void gemm1_mfma(const float* __restrict__ x, const unsigned short* __restrict__ wsw,
                           const float* __restrict__ dinv, unsigned short* __restrict__ h) {
    int t = threadIdx.x;
    int lane = t & 63;
    int wave = t >> 6;
    int m = lane & 15;
    int quad = lane >> 4;
    int rowbase = blockIdx.x * 64 + wave * 16;

    int row = rowbase + m;
    if (row >= N_NODES) row = N_NODES - 1;

    const short8* wv = (const short8*)wsw;

    f32x4 acc[4] = {{0.f,0.f,0.f,0.f},{0.f,0.f,0.f,0.f},{0.f,0.f,0.f,0.f},{0.f,0.f,0.f,0.f}};

    const float* xrow = x + (size_t)row * NF;
#pragma unroll
    for (int kiter = 0; kiter < 8; ++kiter) {
        int k0 = kiter * 32 + quad * 8;
        float4 xa = *(const float4*)&xrow[k0];
        float4 xb = *(const float4*)&xrow[k0 + 4];
        short8 a;
        a[0] = (short)f2bf(xa.x); a[1] = (short)f2bf(xa.y);
        a[2] = (short)f2bf(xa.z); a[3] = (short)f2bf(xa.w);
        a[4] = (short)f2bf(xb.x); a[5] = (short)f2bf(xb.y);
        a[6] = (short)f2bf(xb.z); a[7] = (short)f2bf(xb.w);
#pragma unroll
        for (int nt = 0; nt < 4; ++nt) {
            short8 b = wv[(kiter * 4 + nt) * 64 + lane];
            acc[nt] = __builtin_amdgcn_mfma_f32_16x16x32_bf16(a, b, acc[nt], 0, 0, 0);
        }
    }

    float di[4];
#pragma unroll
    for (int r = 0; r < 4; ++r) {
        int orow = rowbase + quad * 4 + r;
        di[r] = (orow < N_NODES) ? dinv[orow] : 0.f;
    }

#pragma unroll
    for (int nt = 0; nt < 4; ++nt) {
#pragma unroll
        for (int r = 0; r < 4; ++r) {
            int orow = rowbase + quad * 4 + r;
            if (orow < N_NODES) {
                int ocol = nt * 16 + m;
                h[(size_t)orow * HID + ocol] = f2bf(di[r] * acc[nt][r]);
            }
        }
    }
}

// ---------- fused layer-1 aggregation + self-loop + bias + ELU + @W2 (single dispatch) ----------
// agg = dinv[d]*(sum_e ew*h'[s] + h'[d]) + b1;  z' = dinv[d]*(elu(agg)@W2)
__launch_bounds__(256)
__global__ void fused1_kernel(const int* __restrict__ row_ptr, const int2* __restrict__ ebuf,
                              const unsigned short* __restrict__ h,
                              const float* __restrict__ dinv, const float* __restrict__ b1,
                              const float* __restrict__ W2, float* __restrict__ z) {
    int lane = threadIdx.x & 63;
    int d = (blockIdx.x * blockDim.x + threadIdx.x) >> 6;
    if (d >= N_NODES) return;

    int start = row_ptr[d];
    int end = row_ptr[d + 1];
    int f = lane & 15;
    int g = lane >> 4;

    const uint2* h64 = (const uint2*)h;

    float4 acc = make_float4(0.f, 0.f, 0.f, 0.f);

    for (int base = start; base < end; base += 64) {
        int n = end - base; if (n > 64) n = 64;
        int2 e = (lane < n) ? ebuf[base + lane] : make_int2(0, 0);
        int j = 0;
        for (; j + 16 <= n; j += 16) {
            uint2 hp[4]; float w[4];
#pragma unroll
            for (int u = 0; u < 4; ++u) {
                int idx = j + u * 4 + g;
                int s = __shfl(e.x, idx);
                w[u] = __int_as_float(__shfl(e.y, idx));
                hp[u] = h64[(size_t)s * 16 + f];
            }
#pragma unroll
            for (int u = 0; u < 4; ++u) {
                acc.x = fmaf(w[u], bfl(hp[u].x), acc.x);
                acc.y = fmaf(w[u], bfh(hp[u].x), acc.y);
                acc.z = fmaf(w[u], bfl(hp[u].y), acc.z);
                acc.w = fmaf(w[u], bfh(hp[u].y), acc.w);
            }
        }
        for (; j + 4 <= n; j += 4) {
            int idx = j + g;
            int s = __shfl(e.x, idx);
            float w = __int_as_float(__shfl(e.y, idx));
            uint2 hp = h64[(size_t)s * 16 + f];
            acc.x = fmaf(w, bfl(hp.x), acc.x);
            acc.y = fmaf(w, bfh(hp.x), acc.y);
            acc.z = fmaf(w, bfl(hp.y), acc.z);
            acc.w = fmaf(w, bfh(hp.y), acc.w);
        }
        int rem = n - j;
        if (rem > 0) {
            int idx = j + (g < rem ? g : 0);
            int s = __shfl(e.x, idx);
            float w = __int_as_float(__shfl(e.y, idx));
            if (g < rem) {
                uint2 hp = h64[(size_t)s * 16 + f];
                acc.x = fmaf(w, bfl(hp.x), acc.x);
                acc.y = fmaf(w, bfh(hp.x), acc.y);
                acc.z = fmaf(w, bfl(hp.y), acc.z);
                acc.w = fmaf(w, bfh(hp.y), acc.w);
            }
        }
    }

    acc.x += __shfl_down(acc.x, 32); acc.y += __shfl_down(acc.y, 32);
    acc.z += __shfl_down(acc.z, 32); acc.w += __shfl_down(acc.w, 32);
    acc.x += __shfl_down(acc.x, 16); acc.y += __shfl_down(acc.y, 16);
    acc.z += __shfl_down(acc.z, 16); acc.w += __shfl_down(acc.w, 16);

    float di = dinv[d];
    uint2 hd = h64[(size_t)d * 16 + f];   // h' already carries dinv[d]
    float4 b = *(const float4*)&b1[4 * f];
    float4 w2 = *(const float4*)&W2[4 * f];

    float v0 = di * (acc.x + bfl(hd.x)) + b.x;
    float v1 = di * (acc.y + bfh(hd.x)) + b.y;
    float v2 = di * (acc.z + bfl(hd.y)) + b.z;
    float v3 = di * (acc.w + bfh(hd.y)) + b.w;
    v0 = (v0 > 0.f) ? v0 : (__expf(v0) - 1.f);
    v1 = (v1 > 0.f) ? v1 : (__expf(v1) - 1.f);
    v2 = (v2 > 0.f) ? v2 : (__expf(v2) - 1.f);
    v3 = (v3 > 0.f) ? v3 : (__expf(v3) - 1.f);

    float p = v0 * w2.x + v1 * w2.y + v2 * w2.z + v3 * w2.w;
    p += __shfl_down(p, 8);
    p += __shfl_down(p, 4);
    p += __shfl_down(p, 2);
    p += __shfl_down(p, 1);
    if (lane == 0) z[d] = di * p;        // z' = dinv[d] * z
}

// ---------- fused layer-2, 4 dsts per wave (16 lanes each) ----------
// v = dinv[d]*(sum_e ew*z'[s] + z'[d]) + b2; 16-lane reduce stays in-group
// (lane 0 only ever reads lanes 1,2,4,8 combos -> max offset 15).
__launch_bounds__(256)
__global__ void fused2_kernel(const int* __restrict__ row_ptr, const int2* __restrict__ ebuf,
                              const float* __restrict__ z, const float* __restrict__ dinv,
                              const float* __restrict__ b2, float* __restrict__ out) {
    int lane = threadIdx.x & 63;
    int sg = lane >> 4;          // sub-group 0..3 (one dst each)
    int li = lane & 15;
    int d = ((blockIdx.x * blockDim.x + threadIdx.x) >> 6) * 4 + sg;
    if (d >= N_NODES) return;

    int start = row_ptr[d];
    int end = row_ptr[d + 1];

    float acc = 0.0f;
    for (int i = start + li; i < end; i += 16) {
        int2 e = ebuf[i];
        acc = fmaf(__int_as_float(e.y), z[e.x], acc);
    }
    acc += __shfl_down(acc, 8);
    acc += __shfl_down(acc, 4);
    acc += __shfl_down(acc, 2);
    acc += __shfl_down(acc, 1);

    if (li == 0) {
        float di = dinv[d];
        float v = di * (acc + z[d]) + b2[0];
        out[d] = 1.0f / (1.0f + __expf(-v));
    }
}

extern "C" void kernel_launch(void* const* d_in, const int* in_sizes, int n_in,
                              void* d_out, int out_size, void* d_ws, size_t ws_size,
                              hipStream_t stream) {
    const float* x  = (const float*)d_in[0];
    const int*   ei = (const int*)d_in[1];
    const float* ew = (const float*)d_in[2];
    const float* W1 = (const float*)d_in[3];
    const float* b1 = (const float*)d_in[4];
    const float* W2 = (const float*)d_in[5];
    const float* b2 = (const float*)d_in[6];
    float* out = (float*)d_out;

    char* ws = (char*)d_ws;
    unsigned int* blkhist = (unsigned int*)ws;                  ws += (size_t)NP1 * NBUCK * 4;
    unsigned int* blkbase = (unsigned int*)ws;                  ws += (size_t)NBUCK * NP1 * 4;
    unsigned int* total   = (unsigned int*)ws;                  ws += (size_t)NBUCK * 4;
    unsigned int* base    = (unsigned int*)ws;                  ws += (size_t)(NBUCK + 1) * 4;
    float* dinv    = (float*)ws;                                ws += (size_t)N_NODES * 4;
    int*   row_ptr = (int*)ws;                                  ws += (size_t)(N_NODES + 1) * 4;
    int2*  pbuf    = (int2*)ws;                                 ws += (size_t)N_EDGES * 8;
    int2*  ebuf    = (int2*)ws;                                 ws += (size_t)N_EDGES * 8;
    unsigned short* h = (unsigned short*)ws;                    ws += (size_t)N_NODES * HID * 2;
    unsigned short* wsw = (unsigned short*)ws;                  ws += (size_t)NF * HID * 2;
    float* z       = (float*)ws;                                ws += (size_t)N_NODES * 4;

    p1count<<<NP1, 256, 0, stream>>>(ei, blkhist, W1, wsw);
    bktA<<<NBUCK, 256, 0, stream>>>(blkhist, total);
    bktC<<<NBUCK, 256, 0, stream>>>(blkhist, total, blkbase, base);
    p1scatter<<<NP1, 256, 0, stream>>>(ei, ew, blkhist, blkbase, pbuf);
    p2ab<<<NBUCK, 256, 0, stream>>>(pbuf, base, dinv, row_ptr, ebuf);

    gemm1_mfma<<<(N_NODES + 63) / 64, 256, 0, stream>>>(x, wsw, dinv, h);

    int grid1 = (N_NODES * 64 + 255) / 256;      // 1 wave per dst
    fused1_kernel<<<grid1, 256, 0, stream>>>(row_ptr, ebuf, h, dinv, b1, W2, z);

    int grid2 = (N_NODES + 15) / 16;             // 4 dsts per wave, 4 waves per block
    fused2_kernel<<<grid2, 256, 0, stream>>>(row_ptr, ebuf, z, dinv, b2, out);
}